// Round 9
// baseline (2629.412 us; speedup 1.0000x reference)
//
#include <hip/hip_runtime.h>
#include <stdint.h>
#include <string.h>
#include <cmath>

// SpikingYOLO round 9: OpenBLAS-sgemm-faithful conv numerics.
//   Model of the np reference: im2col + BLAS sgemm (single accumulator per C
//   element, vfmadd over k ascending = (ci,kh,kw) ci-major), bias added after,
//   LIF scan elementwise f32 unfused, alpha=0x3F7383C6, beta=0x3F519857.
//   NEW vs R8: kc=384 k-blocking association. For K>384, sgemm accumulates
//   each 384-wide k-block as its own register FMA chain and adds it to C once:
//     conv2 (K=576):  C = round(chain[0,384)) + round(chain[384,576))
//     conv3 (K=1152): C = ((P1 + P2) + P3), Pi = chain over 384-wide blocks
//   conv1 (K=18 < kc): single chain, unchanged from R8 (that change halved the
//   error; spike-input layers are fusion-insensitive so only association left).
// Pipeline: conv1+LIF (T in regs) -> s1 u8; conv2+LIF fused over t -> s2 u8;
//   conv3+LIF+mean -> pooled f32; det 1x1 f32 (comparison is bf16-grain).

#define BB 4
#define TT 10

// ---------------------------------------------------------------- conv1+LIF
// 2->64, 3x3 s1 p1, 128x128. Block 256 = 32 cog(x2co) x 8 px; T in registers.
__global__ __launch_bounds__(256) void conv1_lif(
    const float* __restrict__ x,    // [4,2,128,128,10]
    const float* __restrict__ w1,   // [64,2,3,3]
    const float* __restrict__ b1,   // [64]
    uint8_t* __restrict__ s1,       // [10,4,64,128,128]
    float alpha, float beta)
{
    __shared__ float xs[2][3][10][10];   // [ci][kh][wi][t]
    __shared__ float wsh[18][64];        // [tap][co]
    const int tid = threadIdx.x;
    const int b = blockIdx.z, h = blockIdx.y, w0 = blockIdx.x * 8;

    for (int i = tid; i < 1152; i += 256) {
        int co = i & 63, tap = i >> 6;
        wsh[tap][co] = w1[co * 18 + tap];
    }
    for (int i = tid; i < 600; i += 256) {
        int t = i % 10; int rest = i / 10;
        int wi = rest % 10; rest /= 10;
        int kh = rest % 3; int ci = rest / 3;
        int hh = h - 1 + kh, ww = w0 - 1 + wi;
        float v = 0.f;
        if (hh >= 0 && hh < 128 && ww >= 0 && ww < 128)
            v = x[(((b * 2 + ci) * 128 + hh) * 128 + ww) * 10 + t];
        xs[ci][kh][wi][t] = v;
    }
    __syncthreads();

    const int px  = tid & 7;
    const int cog = (tid >> 3) * 2;   // 2 consecutive co per thread
    float acc[2][10];
#pragma unroll
    for (int c = 0; c < 2; ++c)
#pragma unroll
        for (int t = 0; t < 10; ++t) acc[c][t] = 0.f;

    // K=18 < kc: single FMA chain, k = ci*9 + kh*3 + kw ascending
#pragma unroll
    for (int tap = 0; tap < 18; ++tap) {
        const int ci = tap / 9, kh = (tap % 9) / 3, kw = tap % 3;
        float2 wv = *(const float2*)&wsh[tap][cog];
#pragma unroll
        for (int t = 0; t < 10; ++t) {
            float xv = xs[ci][kh][px + kw][t];
            acc[0][t] = __fmaf_rn(wv.x, xv, acc[0][t]);
            acc[1][t] = __fmaf_rn(wv.y, xv, acc[1][t]);
        }
    }
#pragma unroll
    for (int c = 0; c < 2; ++c) {
        const float bv = b1[cog + c];
        float syn = 0.f, mem = 0.f;
#pragma unroll
        for (int t = 0; t < 10; ++t) {
            float cur = __fadd_rn(acc[c][t], bv);    // bias after conv sum
            syn = __fadd_rn(__fmul_rn(beta, syn), cur);
            mem = __fadd_rn(__fmul_rn(alpha, mem), syn);
            float sp = (mem >= 1.0f) ? 1.0f : 0.0f;
            mem = __fsub_rn(mem, sp);
            s1[(((t * BB + b) * 64 + (cog + c)) * 128 + h) * 128 + w0 + px] = (uint8_t)sp;
        }
    }
}

// ------------------------------- fused stride-2 3x3 conv + LIF (t loop inside)
// Block: 32 co x 8x8 out px, threads 256 = 16 cog(x2co) x 16 pxg(x4px row).
// Per t: ci chunks of 8 ascending; global k = (cc*8+ci)*9 + (kh*3+kw).
// kc=384 association: 'part' chain flushed into 'tot' when k hits 384 / 768.
template<int CIN, int COUT, int HIN, int HOUT, bool MEAN>
__global__ __launch_bounds__(256) void conv_lif(
    const uint8_t* __restrict__ sin,  // [40,CIN,HIN,HIN]
    const float* __restrict__ w,      // [COUT,CIN,3,3]
    const float* __restrict__ bias,   // [COUT]
    uint8_t* __restrict__ sout,       // [40,COUT,HOUT,HOUT]   (MEAN=false)
    float* __restrict__ pooled,       // [4,COUT,HOUT*HOUT]    (MEAN=true)
    float alpha, float beta)
{
    __shared__ float sw[8][9][32];
    __shared__ float ss[8][17][19];
    const int tid = threadIdx.x;
    const int b = blockIdx.z;
    const int co_base = blockIdx.y * 32;
    const int nwt = HOUT / 8;
    const int h0 = (blockIdx.x / nwt) * 8;
    const int w0 = (blockIdx.x % nwt) * 8;
    const int cog = tid >> 4;            // 0..15
    const int co2 = cog * 2;
    const int pxg = tid & 15;
    const int h_off = pxg >> 1;          // 0..7
    const int w_off = (pxg & 1) * 4;     // 0 or 4

    const float bv0 = bias[co_base + co2];
    const float bv1 = bias[co_base + co2 + 1];
    float syn[8], mem[8];
    int cnt[8];
#pragma unroll
    for (int n = 0; n < 8; ++n) { syn[n] = 0.f; mem[n] = 0.f; cnt[n] = 0; }

    for (int t = 0; t < TT; ++t) {
        const int f = t * BB + b;
        float tot[8], part[8];
#pragma unroll
        for (int n = 0; n < 8; ++n) { tot[n] = 0.f; part[n] = 0.f; }

        for (int cc = 0; cc < CIN / 8; ++cc) {
            for (int i = tid; i < 8 * 9 * 32; i += 256) {
                int co = i & 31; int rest = i >> 5;
                int k = rest % 9; int ci = rest / 9;
                sw[ci][k][co] = w[((co_base + co) * CIN + cc * 8 + ci) * 9 + k];
            }
            for (int i = tid; i < 8 * 17 * 17; i += 256) {
                int col = i % 17; int rest = i / 17;
                int row = rest % 17; int ci = rest / 17;
                int r = h0 * 2 - 1 + row, c = w0 * 2 - 1 + col;
                float v = 0.f;
                if (r >= 0 && r < HIN && c >= 0 && c < HIN)
                    v = (float)sin[((f * CIN + cc * 8 + ci) * HIN + r) * HIN + c];
                ss[ci][row][col] = v;
            }
            __syncthreads();
            // sequential f32 FMA chain in k order; kc=384 block flushes
#pragma unroll
            for (int ci = 0; ci < 8; ++ci) {
#pragma unroll
                for (int k = 0; k < 9; ++k) {
                    // flush BEFORE accumulating k-index 384 / 768.
                    // ci*9+k is a compile-time constant per unrolled slot:
                    // only (ci=2,k=6)->cc==5 and (ci=5,k=3)->cc==10 survive.
                    if (cc * 72 + ci * 9 + k == 384 || cc * 72 + ci * 9 + k == 768) {
#pragma unroll
                        for (int n = 0; n < 8; ++n) {
                            tot[n] = __fadd_rn(tot[n], part[n]);
                            part[n] = 0.f;
                        }
                    }
                    const int kh = k / 3, kw = k % 3;
                    float2 wv = *(const float2*)&sw[ci][k][co2];
                    const int row = 2 * h_off + kh;
                    const int cb  = 2 * w_off + kw;
                    float s0  = ss[ci][row][cb];
                    float s1v = ss[ci][row][cb + 2];
                    float s2v = ss[ci][row][cb + 4];
                    float s3v = ss[ci][row][cb + 6];
                    part[0] = __fmaf_rn(wv.x, s0,  part[0]);
                    part[1] = __fmaf_rn(wv.x, s1v, part[1]);
                    part[2] = __fmaf_rn(wv.x, s2v, part[2]);
                    part[3] = __fmaf_rn(wv.x, s3v, part[3]);
                    part[4] = __fmaf_rn(wv.y, s0,  part[4]);
                    part[5] = __fmaf_rn(wv.y, s1v, part[5]);
                    part[6] = __fmaf_rn(wv.y, s2v, part[6]);
                    part[7] = __fmaf_rn(wv.y, s3v, part[7]);
                }
            }
            __syncthreads();
        }
        // LIF step for this t (f32 elementwise, unfused; bias after conv)
        uint32_t pack0 = 0, pack1 = 0;
#pragma unroll
        for (int n = 0; n < 8; ++n) {
            float conv = __fadd_rn(tot[n], part[n]);   // final block add
            float cur = __fadd_rn(conv, (n < 4) ? bv0 : bv1);
            syn[n] = __fadd_rn(__fmul_rn(beta, syn[n]), cur);
            mem[n] = __fadd_rn(__fmul_rn(alpha, mem[n]), syn[n]);
            float sp = (mem[n] >= 1.0f) ? 1.0f : 0.0f;
            mem[n] = __fsub_rn(mem[n], sp);
            if (MEAN) {
                cnt[n] += (int)sp;
            } else {
                uint32_t bit = (uint32_t)sp << ((n & 3) * 8);
                if (n < 4) pack0 |= bit; else pack1 |= bit;
            }
        }
        if (!MEAN) {
            const int hh = h0 + h_off, wc = w0 + w_off;
            *(uint32_t*)&sout[((f * COUT + co_base + co2) * HOUT + hh) * HOUT + wc] = pack0;
            *(uint32_t*)&sout[((f * COUT + co_base + co2 + 1) * HOUT + hh) * HOUT + wc] = pack1;
        }
    }
    if (MEAN) {
        const int hh = h0 + h_off, wc = w0 + w_off;
#pragma unroll
        for (int c = 0; c < 2; ++c) {
            float4 pv = make_float4((float)cnt[c * 4 + 0] / 10.0f,
                                    (float)cnt[c * 4 + 1] / 10.0f,
                                    (float)cnt[c * 4 + 2] / 10.0f,
                                    (float)cnt[c * 4 + 3] / 10.0f);
            *(float4*)&pooled[((b * COUT + co_base + co2 + c) * HOUT + hh) * HOUT + wc] = pv;
        }
    }
}

// ------------------------------------------------------------------ det 1x1
// bf16-grain comparison => f32 rounding detail here is invisible; keep fast.
__global__ __launch_bounds__(256) void det_conv(
    const float* __restrict__ pooled, // [4,256,1024]
    const float* __restrict__ wd,     // [255,256]
    const float* __restrict__ bd,     // [255]
    float* __restrict__ out)          // [4,255,1024]
{
    __shared__ float wt[16][64];
    __shared__ float ps[16][64];
    const int tid = threadIdx.x;
    const int b = blockIdx.z;
    const int o_base = blockIdx.y * 64;
    const int px_base = blockIdx.x * 64;
    const int o_off = (tid >> 4) * 4;
    const int px_off = (tid & 15) * 4;
    float acc[4][4];
#pragma unroll
    for (int c = 0; c < 4; ++c) {
        int o = o_base + o_off + c;
        float bv = (o < 255) ? bd[o] : 0.f;
#pragma unroll
        for (int j = 0; j < 4; ++j) acc[c][j] = bv;
    }
    for (int cc = 0; cc < 16; ++cc) {
        for (int k = tid; k < 1024; k += 256) {
            int o = k & 63, ci = k >> 6;
            wt[ci][o] = (o_base + o < 255) ? wd[(o_base + o) * 256 + cc * 16 + ci] : 0.f;
            ps[ci][o] = pooled[(b * 256 + cc * 16 + ci) * 1024 + px_base + o];
        }
        __syncthreads();
#pragma unroll
        for (int ci = 0; ci < 16; ++ci) {
            float4 wv = *(const float4*)&wt[ci][o_off];
            float4 sv = *(const float4*)&ps[ci][px_off];
            acc[0][0] += wv.x * sv.x; acc[0][1] += wv.x * sv.y;
            acc[0][2] += wv.x * sv.z; acc[0][3] += wv.x * sv.w;
            acc[1][0] += wv.y * sv.x; acc[1][1] += wv.y * sv.y;
            acc[1][2] += wv.y * sv.z; acc[1][3] += wv.y * sv.w;
            acc[2][0] += wv.z * sv.x; acc[2][1] += wv.z * sv.y;
            acc[2][2] += wv.z * sv.z; acc[2][3] += wv.z * sv.w;
            acc[3][0] += wv.w * sv.x; acc[3][1] += wv.w * sv.y;
            acc[3][2] += wv.w * sv.z; acc[3][3] += wv.w * sv.w;
        }
        __syncthreads();
    }
#pragma unroll
    for (int c = 0; c < 4; ++c) {
        int o = o_base + o_off + c;
        if (o < 255)
            *(float4*)&out[(b * 255 + o) * 1024 + px_base + px_off] =
                make_float4(acc[c][0], acc[c][1], acc[c][2], acc[c][3]);
    }
}

extern "C" void kernel_launch(void* const* d_in, const int* in_sizes, int n_in,
                              void* d_out, int out_size, void* d_ws, size_t ws_size,
                              hipStream_t stream) {
    const float* x  = (const float*)d_in[0];
    const float* w1 = (const float*)d_in[1];
    const float* b1 = (const float*)d_in[2];
    const float* w2 = (const float*)d_in[3];
    const float* b2 = (const float*)d_in[4];
    const float* w3 = (const float*)d_in[5];
    const float* b3 = (const float*)d_in[6];
    const float* wd = (const float*)d_in[7];
    const float* bd = (const float*)d_in[8];
    float* out = (float*)d_out;

    // ws layout: s1 u8 [40][64][128][128] @0 (41,943,040)
    //            s2 u8 [40][128][64][64]  @41,943,040 (20,971,520)
    //            pooled f32 [4][256][1024] @62,914,560 (4,194,304)   total 67MB
    uint8_t* wsb = (uint8_t*)d_ws;
    uint8_t* s1     = wsb;
    uint8_t* s2     = wsb + 41943040u;
    float*   pooled = (float*)(wsb + 62914560u);

    // f32 LIF constants: alpha = e^-0.05f (razor-midpoint upper, glibc/CR),
    // beta = e^-0.2f (unambiguous).
    float alpha, beta;
    { uint32_t ab = 0x3F7383C6u; memcpy(&alpha, &ab, 4); }
    { uint32_t bb = 0x3F519857u; memcpy(&beta,  &bb, 4); }

    conv1_lif<<<dim3(16, 128, 4), 256, 0, stream>>>(x, w1, b1, s1, alpha, beta);
    conv_lif<64, 128, 128, 64, false><<<dim3(64, 4, 4), 256, 0, stream>>>(
        s1, w2, b2, s2, nullptr, alpha, beta);
    conv_lif<128, 256, 64, 32, true><<<dim3(16, 8, 4), 256, 0, stream>>>(
        s2, w3, b3, nullptr, pooled, alpha, beta);
    det_conv<<<dim3(16, 4, 4), 256, 0, stream>>>(pooled, wd, bd, out);
}

// Round 10
// 1284.867 us; speedup vs baseline: 2.0464x; 2.0464x over previous
//
#include <hip/hip_runtime.h>
#include <stdint.h>
#include <string.h>
#include <cmath>

// SpikingYOLO round 10: performance restructure, numerics BIT-IDENTICAL to R9
// (R9 passed: FMA-sequential f32 conv, k=(ci,kh,kw) ascending, kc=384 block
// association, bias after, unfused f32 LIF, alpha=0x3F7383C6 beta=0x3F519857).
//
// conv2/conv3 rewrite ("conv_lif_g"): no LDS, no barriers.
//  - thread tile 4co x 4px (one out-row segment); per (ci,kh) 3 global dword
//    loads of u8 spikes (12B window, L1-resident) + u8->f32 via cvt_f32_ubyte.
//  - weights pre-transposed to wt[k][co] in ws (wtrans kernel) so the 4-co
//    weight vector address is block-uniform -> scalar s_load, FMA from SGPR.
//  - kc=384 flush points peeled at compile time (ci=42 tap6; ci=85 tap3).
//  - spikes stored with 256B headroom so the left-edge aligned window (col -4)
//    stays in-buffer; masked to zero (exact pad semantics).

#define BB 4
#define TT 10

// ---------------------------------------------------------------- conv1+LIF
// unchanged from R9 (numerics sacred)
__global__ __launch_bounds__(256) void conv1_lif(
    const float* __restrict__ x,    // [4,2,128,128,10]
    const float* __restrict__ w1,   // [64,2,3,3]
    const float* __restrict__ b1,   // [64]
    uint8_t* __restrict__ s1,       // [10,4,64,128,128]
    float alpha, float beta)
{
    __shared__ float xs[2][3][10][10];   // [ci][kh][wi][t]
    __shared__ float wsh[18][64];        // [tap][co]
    const int tid = threadIdx.x;
    const int b = blockIdx.z, h = blockIdx.y, w0 = blockIdx.x * 8;

    for (int i = tid; i < 1152; i += 256) {
        int co = i & 63, tap = i >> 6;
        wsh[tap][co] = w1[co * 18 + tap];
    }
    for (int i = tid; i < 600; i += 256) {
        int t = i % 10; int rest = i / 10;
        int wi = rest % 10; rest /= 10;
        int kh = rest % 3; int ci = rest / 3;
        int hh = h - 1 + kh, ww = w0 - 1 + wi;
        float v = 0.f;
        if (hh >= 0 && hh < 128 && ww >= 0 && ww < 128)
            v = x[(((b * 2 + ci) * 128 + hh) * 128 + ww) * 10 + t];
        xs[ci][kh][wi][t] = v;
    }
    __syncthreads();

    const int px  = tid & 7;
    const int cog = (tid >> 3) * 2;
    float acc[2][10];
#pragma unroll
    for (int c = 0; c < 2; ++c)
#pragma unroll
        for (int t = 0; t < 10; ++t) acc[c][t] = 0.f;

#pragma unroll
    for (int tap = 0; tap < 18; ++tap) {
        const int ci = tap / 9, kh = (tap % 9) / 3, kw = tap % 3;
        float2 wv = *(const float2*)&wsh[tap][cog];
#pragma unroll
        for (int t = 0; t < 10; ++t) {
            float xv = xs[ci][kh][px + kw][t];
            acc[0][t] = __fmaf_rn(wv.x, xv, acc[0][t]);
            acc[1][t] = __fmaf_rn(wv.y, xv, acc[1][t]);
        }
    }
#pragma unroll
    for (int c = 0; c < 2; ++c) {
        const float bv = b1[cog + c];
        float syn = 0.f, mem = 0.f;
#pragma unroll
        for (int t = 0; t < 10; ++t) {
            float cur = __fadd_rn(acc[c][t], bv);
            syn = __fadd_rn(__fmul_rn(beta, syn), cur);
            mem = __fadd_rn(__fmul_rn(alpha, mem), syn);
            float sp = (mem >= 1.0f) ? 1.0f : 0.0f;
            mem = __fsub_rn(mem, sp);
            s1[(((t * BB + b) * 64 + (cog + c)) * 128 + h) * 128 + w0 + px] = (uint8_t)sp;
        }
    }
}

// --------------------------------------------------- weight transpose kernel
// wt[k][co] = w[co][k], k = ci*9+kh*3+kw (matches OIHW flat order)
__global__ __launch_bounds__(256) void wtrans(
    const float* __restrict__ w, float* __restrict__ wt, int K, int COUT)
{
    int i = blockIdx.x * 256 + threadIdx.x;
    if (i < K * COUT) {
        int k = i / COUT, co = i - k * COUT;
        wt[i] = w[co * K + k];
    }
}

// ------------------------------------------------- per-ci conv taps (inlined)
template<int CIN, int COUT, int HIN, int KHB, int KHE>
__device__ __forceinline__ void conv_ci(
    int ci, const uint8_t* __restrict__ fb, const float* __restrict__ wt,
    int cob, int off0, int off1, int off2,
    uint32_t mA0, uint32_t mA12, uint32_t mB0, float part[16])
{
    const uint8_t* p = fb + ci * HIN * HIN;
    const int offs[3] = {off0, off1, off2};
    uint32_t dw[3][3];
#pragma unroll
    for (int kh = KHB; kh < KHE; ++kh) {
        const uint8_t* q = p + offs[kh];
        dw[kh][0] = *(const uint32_t*)(q);
        dw[kh][1] = *(const uint32_t*)(q + 4);
        dw[kh][2] = *(const uint32_t*)(q + 8);
    }
#pragma unroll
    for (int kh = KHB; kh < KHE; ++kh) {
        uint32_t e0 = dw[kh][0] & ((kh == 0) ? mA0 : mB0);
        uint32_t e1 = dw[kh][1] & ((kh == 0) ? mA12 : 0xFFFFFFFFu);
        uint32_t e2 = dw[kh][2] & ((kh == 0) ? mA12 : 0xFFFFFFFFu);
        // sv[c] = spike at in-col (8*w4-1+c) = byte (c+3) of the 12B window
        float sv[9];
        sv[0] = (float)(e0 >> 24);
        sv[1] = (float)(e1 & 0xffu);
        sv[2] = (float)((e1 >> 8) & 0xffu);
        sv[3] = (float)((e1 >> 16) & 0xffu);
        sv[4] = (float)(e1 >> 24);
        sv[5] = (float)(e2 & 0xffu);
        sv[6] = (float)((e2 >> 8) & 0xffu);
        sv[7] = (float)((e2 >> 16) & 0xffu);
        sv[8] = (float)(e2 >> 24);
#pragma unroll
        for (int kw = 0; kw < 3; ++kw) {
            const float* wp = wt + (ci * 9 + kh * 3 + kw) * COUT + cob; // uniform -> s_load
            const float w0 = wp[0], w1 = wp[1], w2 = wp[2], w3 = wp[3];
#pragma unroll
            for (int j = 0; j < 4; ++j) {
                const float s = sv[2 * j + kw];
                part[0 + j]  = __fmaf_rn(w0, s, part[0 + j]);
                part[4 + j]  = __fmaf_rn(w1, s, part[4 + j]);
                part[8 + j]  = __fmaf_rn(w2, s, part[8 + j]);
                part[12 + j] = __fmaf_rn(w3, s, part[12 + j]);
            }
        }
    }
}

// ---------------------------- fused stride-2 3x3 conv + LIF, global-direct
// thread: 4co x 4px; block 256 thr; no LDS, no barriers.
template<int CIN, int COUT, int HIN, int HOUT, int WTH, bool MEAN,
         int F1CI, int F1KH, int F2CI, int F2KH>
__global__ __launch_bounds__(256) void conv_lif_g(
    const uint8_t* __restrict__ sin,   // [40,CIN,HIN,HIN]
    const float* __restrict__ wt,      // [CIN*9][COUT] transposed
    const float* __restrict__ bias,    // [COUT]
    uint8_t* __restrict__ sout,        // [40,COUT,HOUT,HOUT] (MEAN=false)
    float* __restrict__ pooled,        // [4,COUT,HOUT*HOUT]  (MEAN=true)
    float alpha, float beta)
{
    const int tid = threadIdx.x;
    const int w4  = tid & (WTH - 1);
    const int hh  = blockIdx.x * (256 / WTH) + (tid / WTH);
    const int co4 = blockIdx.y;
    const int b   = blockIdx.z;
    const int wb  = w4 * 4;
    const int cob = co4 * 4;

    const uint32_t full = 0xFFFFFFFFu;
    const uint32_t mB0  = (w4 == 0) ? 0u : full;   // window cols -4..-1 pad
    const uint32_t mA0  = (hh == 0) ? 0u : mB0;    // + row -1 pad (kh==0)
    const uint32_t mA12 = (hh == 0) ? 0u : full;
    const int acl  = 8 * w4 - 4;                   // aligned window start col
    const int off0 = ((hh == 0) ? 0 : (2 * hh - 1)) * HIN + acl;
    const int off1 = (2 * hh) * HIN + acl;
    const int off2 = (2 * hh + 1) * HIN + acl;

    const float bv[4] = {bias[cob], bias[cob + 1], bias[cob + 2], bias[cob + 3]};

    float syn[16], mem[16], sum[16];
#pragma unroll
    for (int n = 0; n < 16; ++n) { syn[n] = 0.f; mem[n] = 0.f; sum[n] = 0.f; }

    for (int t = 0; t < TT; ++t) {
        const uint8_t* fb = sin + (t * BB + b) * CIN * HIN * HIN;
        float part[16], tot[16];
#pragma unroll
        for (int n = 0; n < 16; ++n) { part[n] = 0.f; tot[n] = 0.f; }

        for (int ci = 0; ci < F1CI; ++ci)
            conv_ci<CIN,COUT,HIN,0,3>(ci, fb, wt, cob, off0,off1,off2, mA0,mA12,mB0, part);
        // kc flush #1 at global k=384 (ci=F1CI, tap F1KH*3)
        conv_ci<CIN,COUT,HIN,0,F1KH>(F1CI, fb, wt, cob, off0,off1,off2, mA0,mA12,mB0, part);
#pragma unroll
        for (int n = 0; n < 16; ++n) { tot[n] = __fadd_rn(tot[n], part[n]); part[n] = 0.f; }
        conv_ci<CIN,COUT,HIN,F1KH,3>(F1CI, fb, wt, cob, off0,off1,off2, mA0,mA12,mB0, part);
        if constexpr (F2CI < CIN) {
            for (int ci = F1CI + 1; ci < F2CI; ++ci)
                conv_ci<CIN,COUT,HIN,0,3>(ci, fb, wt, cob, off0,off1,off2, mA0,mA12,mB0, part);
            // kc flush #2 at global k=768 (ci=F2CI, tap F2KH*3)
            conv_ci<CIN,COUT,HIN,0,F2KH>(F2CI, fb, wt, cob, off0,off1,off2, mA0,mA12,mB0, part);
#pragma unroll
            for (int n = 0; n < 16; ++n) { tot[n] = __fadd_rn(tot[n], part[n]); part[n] = 0.f; }
            conv_ci<CIN,COUT,HIN,F2KH,3>(F2CI, fb, wt, cob, off0,off1,off2, mA0,mA12,mB0, part);
            for (int ci = F2CI + 1; ci < CIN; ++ci)
                conv_ci<CIN,COUT,HIN,0,3>(ci, fb, wt, cob, off0,off1,off2, mA0,mA12,mB0, part);
        } else {
            for (int ci = F1CI + 1; ci < CIN; ++ci)
                conv_ci<CIN,COUT,HIN,0,3>(ci, fb, wt, cob, off0,off1,off2, mA0,mA12,mB0, part);
        }

        // LIF step (f32 elementwise, unfused; bias after conv; final block add)
        uint32_t pk[4] = {0u, 0u, 0u, 0u};
#pragma unroll
        for (int n = 0; n < 16; ++n) {
            float conv = __fadd_rn(tot[n], part[n]);
            float cur  = __fadd_rn(conv, bv[n >> 2]);
            syn[n] = __fadd_rn(__fmul_rn(beta, syn[n]), cur);
            mem[n] = __fadd_rn(__fmul_rn(alpha, mem[n]), syn[n]);
            bool sc = (mem[n] >= 1.0f);
            float sp = sc ? 1.0f : 0.0f;
            mem[n] = __fsub_rn(mem[n], sp);
            if (MEAN) sum[n] = __fadd_rn(sum[n], sp);
            else      pk[n >> 2] |= (sc ? 1u : 0u) << ((n & 3) * 8);
        }
        if (!MEAN) {
            const int f = t * BB + b;
#pragma unroll
            for (int c = 0; c < 4; ++c)
                *(uint32_t*)&sout[((f * COUT + cob + c) * HOUT + hh) * HOUT + wb] = pk[c];
        }
    }
    if (MEAN) {
#pragma unroll
        for (int c = 0; c < 4; ++c)
            *(float4*)&pooled[((b * COUT + cob + c) * HOUT + hh) * HOUT + wb] =
                make_float4(sum[c * 4 + 0] / 10.0f, sum[c * 4 + 1] / 10.0f,
                            sum[c * 4 + 2] / 10.0f, sum[c * 4 + 3] / 10.0f);
    }
}

// ------------------------------------------------------------------ det 1x1
// unchanged from R9 (bf16-grain comparison -> rounding detail invisible)
__global__ __launch_bounds__(256) void det_conv(
    const float* __restrict__ pooled, // [4,256,1024]
    const float* __restrict__ wd,     // [255,256]
    const float* __restrict__ bd,     // [255]
    float* __restrict__ out)          // [4,255,1024]
{
    __shared__ float wtl[16][64];
    __shared__ float ps[16][64];
    const int tid = threadIdx.x;
    const int b = blockIdx.z;
    const int o_base = blockIdx.y * 64;
    const int px_base = blockIdx.x * 64;
    const int o_off = (tid >> 4) * 4;
    const int px_off = (tid & 15) * 4;
    float acc[4][4];
#pragma unroll
    for (int c = 0; c < 4; ++c) {
        int o = o_base + o_off + c;
        float bv = (o < 255) ? bd[o] : 0.f;
#pragma unroll
        for (int j = 0; j < 4; ++j) acc[c][j] = bv;
    }
    for (int cc = 0; cc < 16; ++cc) {
        for (int k = tid; k < 1024; k += 256) {
            int o = k & 63, ci = k >> 6;
            wtl[ci][o] = (o_base + o < 255) ? wd[(o_base + o) * 256 + cc * 16 + ci] : 0.f;
            ps[ci][o] = pooled[(b * 256 + cc * 16 + ci) * 1024 + px_base + o];
        }
        __syncthreads();
#pragma unroll
        for (int ci = 0; ci < 16; ++ci) {
            float4 wv = *(const float4*)&wtl[ci][o_off];
            float4 sv = *(const float4*)&ps[ci][px_off];
            acc[0][0] += wv.x * sv.x; acc[0][1] += wv.x * sv.y;
            acc[0][2] += wv.x * sv.z; acc[0][3] += wv.x * sv.w;
            acc[1][0] += wv.y * sv.x; acc[1][1] += wv.y * sv.y;
            acc[1][2] += wv.y * sv.z; acc[1][3] += wv.y * sv.w;
            acc[2][0] += wv.z * sv.x; acc[2][1] += wv.z * sv.y;
            acc[2][2] += wv.z * sv.z; acc[2][3] += wv.z * sv.w;
            acc[3][0] += wv.w * sv.x; acc[3][1] += wv.w * sv.y;
            acc[3][2] += wv.w * sv.z; acc[3][3] += wv.w * sv.w;
        }
        __syncthreads();
    }
#pragma unroll
    for (int c = 0; c < 4; ++c) {
        int o = o_base + o_off + c;
        if (o < 255)
            *(float4*)&out[(b * 255 + o) * 1024 + px_base + px_off] =
                make_float4(acc[c][0], acc[c][1], acc[c][2], acc[c][3]);
    }
}

extern "C" void kernel_launch(void* const* d_in, const int* in_sizes, int n_in,
                              void* d_out, int out_size, void* d_ws, size_t ws_size,
                              hipStream_t stream) {
    const float* x  = (const float*)d_in[0];
    const float* w1 = (const float*)d_in[1];
    const float* b1 = (const float*)d_in[2];
    const float* w2 = (const float*)d_in[3];
    const float* b2 = (const float*)d_in[4];
    const float* w3 = (const float*)d_in[5];
    const float* b3 = (const float*)d_in[6];
    const float* wd = (const float*)d_in[7];
    const float* bd = (const float*)d_in[8];
    float* out = (float*)d_out;

    // ws layout (256B headroom before s1 for the left-edge aligned window):
    //   s1  u8  [40][64][128][128] @ 256        (41,943,040)
    //   s2  u8  [40][128][64][64]  @ 41,943,296 (20,971,520)
    //   pooled f32 [4][256][1024]  @ 62,914,816 (4,194,304)
    //   wt2 f32 [576][128]         @ 67,109,120 (294,912)
    //   wt3 f32 [1152][256]        @ 67,404,032 (1,179,648)   end 68,583,680
    uint8_t* wsb = (uint8_t*)d_ws;
    uint8_t* s1     = wsb + 256;
    uint8_t* s2     = wsb + 41943296u;
    float*   pooled = (float*)(wsb + 62914816u);
    float*   wt2    = (float*)(wsb + 67109120u);
    float*   wt3    = (float*)(wsb + 67404032u);

    float alpha, beta;
    { uint32_t ab = 0x3F7383C6u; memcpy(&alpha, &ab, 4); }  // e^-0.05f
    { uint32_t bb = 0x3F519857u; memcpy(&beta,  &bb, 4); }  // e^-0.2f

    wtrans<<<288, 256, 0, stream>>>(w2, wt2, 576, 128);
    wtrans<<<1152, 256, 0, stream>>>(w3, wt3, 1152, 256);
    conv1_lif<<<dim3(16, 128, 4), 256, 0, stream>>>(x, w1, b1, s1, alpha, beta);
    // L2: 64->128, 128->64. thread 4co x 4px; block: 16 w4 x 16 rows; grid 4x32x4
    conv_lif_g<64, 128, 128, 64, 16, false, 42, 2, 64, 0>
        <<<dim3(4, 32, 4), 256, 0, stream>>>(s1, wt2, b2, s2, nullptr, alpha, beta);
    // L3: 128->256, 64->32, +mean. block: 8 w4 x 32 rows; grid 1x64x4
    conv_lif_g<128, 256, 64, 32, 8, true, 42, 2, 85, 1>
        <<<dim3(1, 64, 4), 256, 0, stream>>>(s2, wt3, b3, nullptr, pooled, alpha, beta);
    det_conv<<<dim3(16, 4, 4), 256, 0, stream>>>(pooled, wd, bd, out);
}

// Round 11
// 790.801 us; speedup vs baseline: 3.3250x; 1.6248x over previous
//
#include <hip/hip_runtime.h>
#include <stdint.h>
#include <string.h>
#include <cmath>

// SpikingYOLO round 11: split conv (t-parallel) from LIF (t-sequential).
// Numerics BIT-IDENTICAL to R9/R10 (FMA-sequential f32 conv, k=(ci,kh,kw)
// ascending, kc=384 block association, bias after, unfused f32 LIF,
// alpha=0x3F7383C6 beta=0x3F519857).
// R10 post-mortem: fused t-loop capped the grid at 1-2 blocks/CU ->
// OccupancyPercent 11.8, VALUBusy 38.8 (latency-bound). This round: conv_g
// writes pre-bias currents f32 for all 40 frames (grid x10), lif_s/lif_mean
// re-run the identical scan. Same FMA chains, same flush adds -> bit-exact.

#define BB 4
#define TT 10

// ---------------------------------------------------------------- conv1+LIF
// unchanged from R9 (numerics sacred; small: 8192 blocks)
__global__ __launch_bounds__(256) void conv1_lif(
    const float* __restrict__ x,    // [4,2,128,128,10]
    const float* __restrict__ w1,   // [64,2,3,3]
    const float* __restrict__ b1,   // [64]
    uint8_t* __restrict__ s1,       // [10,4,64,128,128]
    float alpha, float beta)
{
    __shared__ float xs[2][3][10][10];   // [ci][kh][wi][t]
    __shared__ float wsh[18][64];        // [tap][co]
    const int tid = threadIdx.x;
    const int b = blockIdx.z, h = blockIdx.y, w0 = blockIdx.x * 8;

    for (int i = tid; i < 1152; i += 256) {
        int co = i & 63, tap = i >> 6;
        wsh[tap][co] = w1[co * 18 + tap];
    }
    for (int i = tid; i < 600; i += 256) {
        int t = i % 10; int rest = i / 10;
        int wi = rest % 10; rest /= 10;
        int kh = rest % 3; int ci = rest / 3;
        int hh = h - 1 + kh, ww = w0 - 1 + wi;
        float v = 0.f;
        if (hh >= 0 && hh < 128 && ww >= 0 && ww < 128)
            v = x[(((b * 2 + ci) * 128 + hh) * 128 + ww) * 10 + t];
        xs[ci][kh][wi][t] = v;
    }
    __syncthreads();

    const int px  = tid & 7;
    const int cog = (tid >> 3) * 2;
    float acc[2][10];
#pragma unroll
    for (int c = 0; c < 2; ++c)
#pragma unroll
        for (int t = 0; t < 10; ++t) acc[c][t] = 0.f;

#pragma unroll
    for (int tap = 0; tap < 18; ++tap) {
        const int ci = tap / 9, kh = (tap % 9) / 3, kw = tap % 3;
        float2 wv = *(const float2*)&wsh[tap][cog];
#pragma unroll
        for (int t = 0; t < 10; ++t) {
            float xv = xs[ci][kh][px + kw][t];
            acc[0][t] = __fmaf_rn(wv.x, xv, acc[0][t]);
            acc[1][t] = __fmaf_rn(wv.y, xv, acc[1][t]);
        }
    }
#pragma unroll
    for (int c = 0; c < 2; ++c) {
        const float bv = b1[cog + c];
        float syn = 0.f, mem = 0.f;
#pragma unroll
        for (int t = 0; t < 10; ++t) {
            float cur = __fadd_rn(acc[c][t], bv);
            syn = __fadd_rn(__fmul_rn(beta, syn), cur);
            mem = __fadd_rn(__fmul_rn(alpha, mem), syn);
            float sp = (mem >= 1.0f) ? 1.0f : 0.0f;
            mem = __fsub_rn(mem, sp);
            s1[(((t * BB + b) * 64 + (cog + c)) * 128 + h) * 128 + w0 + px] = (uint8_t)sp;
        }
    }
}

// --------------------------------------------------- weight transpose kernel
__global__ __launch_bounds__(256) void wtrans(
    const float* __restrict__ w, float* __restrict__ wt, int K, int COUT)
{
    int i = blockIdx.x * 256 + threadIdx.x;
    if (i < K * COUT) {
        int k = i / COUT, co = i - k * COUT;
        wt[i] = w[co * K + k];
    }
}

// ------------------------------------------------- per-ci conv taps (inlined)
template<int CIN, int COUT, int HIN, int KHB, int KHE>
__device__ __forceinline__ void conv_ci(
    int ci, const uint8_t* __restrict__ fb, const float* __restrict__ wt,
    int cob, int off0, int off1, int off2,
    uint32_t mA0, uint32_t mA12, uint32_t mB0, float part[16])
{
    const uint8_t* p = fb + ci * HIN * HIN;
    const int offs[3] = {off0, off1, off2};
    uint32_t dw[3][3];
#pragma unroll
    for (int kh = KHB; kh < KHE; ++kh) {
        const uint8_t* q = p + offs[kh];
        dw[kh][0] = *(const uint32_t*)(q);
        dw[kh][1] = *(const uint32_t*)(q + 4);
        dw[kh][2] = *(const uint32_t*)(q + 8);
    }
#pragma unroll
    for (int kh = KHB; kh < KHE; ++kh) {
        uint32_t e0 = dw[kh][0] & ((kh == 0) ? mA0 : mB0);
        uint32_t e1 = dw[kh][1] & ((kh == 0) ? mA12 : 0xFFFFFFFFu);
        uint32_t e2 = dw[kh][2] & ((kh == 0) ? mA12 : 0xFFFFFFFFu);
        float sv[9];
        sv[0] = (float)(e0 >> 24);
        sv[1] = (float)(e1 & 0xffu);
        sv[2] = (float)((e1 >> 8) & 0xffu);
        sv[3] = (float)((e1 >> 16) & 0xffu);
        sv[4] = (float)(e1 >> 24);
        sv[5] = (float)(e2 & 0xffu);
        sv[6] = (float)((e2 >> 8) & 0xffu);
        sv[7] = (float)((e2 >> 16) & 0xffu);
        sv[8] = (float)(e2 >> 24);
#pragma unroll
        for (int kw = 0; kw < 3; ++kw) {
            const float* wp = wt + (ci * 9 + kh * 3 + kw) * COUT + cob; // uniform -> s_load
            const float w0 = wp[0], w1 = wp[1], w2 = wp[2], w3 = wp[3];
#pragma unroll
            for (int j = 0; j < 4; ++j) {
                const float s = sv[2 * j + kw];
                part[0 + j]  = __fmaf_rn(w0, s, part[0 + j]);
                part[4 + j]  = __fmaf_rn(w1, s, part[4 + j]);
                part[8 + j]  = __fmaf_rn(w2, s, part[8 + j]);
                part[12 + j] = __fmaf_rn(w3, s, part[12 + j]);
            }
        }
    }
}

// -------------------- stride-2 3x3 conv, t-parallel, currents out (no LIF)
// thread: 4co x 4px; grid (HOUT/(256/WTH), COUT/4, 40); no LDS, no barriers.
template<int CIN, int COUT, int HIN, int HOUT, int WTH,
         int F1CI, int F1KH, int F2CI, int F2KH>
__global__ __launch_bounds__(256) void conv_g(
    const uint8_t* __restrict__ sin,   // [40,CIN,HIN,HIN]
    const float* __restrict__ wt,      // [CIN*9][COUT] transposed
    float* __restrict__ cur)           // [40,COUT,HOUT,HOUT] pre-bias currents
{
    const int tid = threadIdx.x;
    const int w4  = tid & (WTH - 1);
    const int hh  = blockIdx.x * (256 / WTH) + (tid / WTH);
    const int cob = blockIdx.y * 4;
    const int f   = blockIdx.z;
    const int wb  = w4 * 4;

    const uint32_t full = 0xFFFFFFFFu;
    const uint32_t mB0  = (w4 == 0) ? 0u : full;
    const uint32_t mA0  = (hh == 0) ? 0u : mB0;
    const uint32_t mA12 = (hh == 0) ? 0u : full;
    const int acl  = 8 * w4 - 4;
    const int off0 = ((hh == 0) ? 0 : (2 * hh - 1)) * HIN + acl;
    const int off1 = (2 * hh) * HIN + acl;
    const int off2 = (2 * hh + 1) * HIN + acl;

    const uint8_t* fb = sin + f * CIN * HIN * HIN;
    float part[16], tot[16];
#pragma unroll
    for (int n = 0; n < 16; ++n) { part[n] = 0.f; tot[n] = 0.f; }

    for (int ci = 0; ci < F1CI; ++ci)
        conv_ci<CIN,COUT,HIN,0,3>(ci, fb, wt, cob, off0,off1,off2, mA0,mA12,mB0, part);
    // kc flush #1 at global k=384
    conv_ci<CIN,COUT,HIN,0,F1KH>(F1CI, fb, wt, cob, off0,off1,off2, mA0,mA12,mB0, part);
#pragma unroll
    for (int n = 0; n < 16; ++n) { tot[n] = __fadd_rn(tot[n], part[n]); part[n] = 0.f; }
    conv_ci<CIN,COUT,HIN,F1KH,3>(F1CI, fb, wt, cob, off0,off1,off2, mA0,mA12,mB0, part);
    if constexpr (F2CI < CIN) {
        for (int ci = F1CI + 1; ci < F2CI; ++ci)
            conv_ci<CIN,COUT,HIN,0,3>(ci, fb, wt, cob, off0,off1,off2, mA0,mA12,mB0, part);
        // kc flush #2 at global k=768
        conv_ci<CIN,COUT,HIN,0,F2KH>(F2CI, fb, wt, cob, off0,off1,off2, mA0,mA12,mB0, part);
#pragma unroll
        for (int n = 0; n < 16; ++n) { tot[n] = __fadd_rn(tot[n], part[n]); part[n] = 0.f; }
        conv_ci<CIN,COUT,HIN,F2KH,3>(F2CI, fb, wt, cob, off0,off1,off2, mA0,mA12,mB0, part);
        for (int ci = F2CI + 1; ci < CIN; ++ci)
            conv_ci<CIN,COUT,HIN,0,3>(ci, fb, wt, cob, off0,off1,off2, mA0,mA12,mB0, part);
    } else {
        for (int ci = F1CI + 1; ci < CIN; ++ci)
            conv_ci<CIN,COUT,HIN,0,3>(ci, fb, wt, cob, off0,off1,off2, mA0,mA12,mB0, part);
    }

#pragma unroll
    for (int c = 0; c < 4; ++c) {
        float4 v = make_float4(__fadd_rn(tot[c*4+0], part[c*4+0]),
                               __fadd_rn(tot[c*4+1], part[c*4+1]),
                               __fadd_rn(tot[c*4+2], part[c*4+2]),
                               __fadd_rn(tot[c*4+3], part[c*4+3]));
        *(float4*)&cur[((f * COUT + cob + c) * HOUT + hh) * HOUT + wb] = v;
    }
}

// ------------------------------------------ LIF scan over currents -> spikes
// grid (HOUT*HOUT/1024, COUT, 4); thread = 4 consecutive px of one (b,co).
template<int COUT, int HW>
__global__ __launch_bounds__(256) void lif_s(
    const float* __restrict__ cur, const float* __restrict__ bias,
    uint8_t* __restrict__ spk, float alpha, float beta)
{
    const int px = (blockIdx.x * 256 + threadIdx.x) * 4;
    const int co = blockIdx.y;
    const int b  = blockIdx.z;
    const float bv = bias[co];
    float syn[4] = {0.f,0.f,0.f,0.f}, mem[4] = {0.f,0.f,0.f,0.f};
    for (int t = 0; t < TT; ++t) {
        const int idx = ((t * BB + b) * COUT + co) * HW + px;
        float4 v = *(const float4*)&cur[idx];
        const float vv[4] = {v.x, v.y, v.z, v.w};
        uint32_t pk = 0;
#pragma unroll
        for (int j = 0; j < 4; ++j) {
            float c = __fadd_rn(vv[j], bv);
            syn[j] = __fadd_rn(__fmul_rn(beta, syn[j]), c);
            mem[j] = __fadd_rn(__fmul_rn(alpha, mem[j]), syn[j]);
            bool sc = (mem[j] >= 1.0f);
            mem[j] = __fsub_rn(mem[j], sc ? 1.0f : 0.0f);
            pk |= (sc ? 1u : 0u) << (j * 8);
        }
        *(uint32_t*)&spk[idx] = pk;
    }
}

// ------------------------------------- LIF + time-mean -> pooled (layer 3)
template<int COUT, int HW>
__global__ __launch_bounds__(256) void lif_mean(
    const float* __restrict__ cur, const float* __restrict__ bias,
    float* __restrict__ pooled, float alpha, float beta)
{
    const int px = (blockIdx.x * 256 + threadIdx.x) * 4;
    const int co = blockIdx.y;
    const int b  = blockIdx.z;
    const float bv = bias[co];
    float syn[4] = {0.f,0.f,0.f,0.f}, mem[4] = {0.f,0.f,0.f,0.f};
    float sum[4] = {0.f,0.f,0.f,0.f};
    for (int t = 0; t < TT; ++t) {
        const int idx = ((t * BB + b) * COUT + co) * HW + px;
        float4 v = *(const float4*)&cur[idx];
        const float vv[4] = {v.x, v.y, v.z, v.w};
#pragma unroll
        for (int j = 0; j < 4; ++j) {
            float c = __fadd_rn(vv[j], bv);
            syn[j] = __fadd_rn(__fmul_rn(beta, syn[j]), c);
            mem[j] = __fadd_rn(__fmul_rn(alpha, mem[j]), syn[j]);
            bool sc = (mem[j] >= 1.0f);
            float sp = sc ? 1.0f : 0.0f;
            mem[j] = __fsub_rn(mem[j], sp);
            sum[j] = __fadd_rn(sum[j], sp);
        }
    }
    *(float4*)&pooled[(b * COUT + co) * HW + px] =
        make_float4(sum[0] / 10.0f, sum[1] / 10.0f, sum[2] / 10.0f, sum[3] / 10.0f);
}

// ------------------------------------------------------------------ det 1x1
__global__ __launch_bounds__(256) void det_conv(
    const float* __restrict__ pooled, // [4,256,1024]
    const float* __restrict__ wd,     // [255,256]
    const float* __restrict__ bd,     // [255]
    float* __restrict__ out)          // [4,255,1024]
{
    __shared__ float wtl[16][64];
    __shared__ float ps[16][64];
    const int tid = threadIdx.x;
    const int b = blockIdx.z;
    const int o_base = blockIdx.y * 64;
    const int px_base = blockIdx.x * 64;
    const int o_off = (tid >> 4) * 4;
    const int px_off = (tid & 15) * 4;
    float acc[4][4];
#pragma unroll
    for (int c = 0; c < 4; ++c) {
        int o = o_base + o_off + c;
        float bv = (o < 255) ? bd[o] : 0.f;
#pragma unroll
        for (int j = 0; j < 4; ++j) acc[c][j] = bv;
    }
    for (int cc = 0; cc < 16; ++cc) {
        for (int k = tid; k < 1024; k += 256) {
            int o = k & 63, ci = k >> 6;
            wtl[ci][o] = (o_base + o < 255) ? wd[(o_base + o) * 256 + cc * 16 + ci] : 0.f;
            ps[ci][o] = pooled[(b * 256 + cc * 16 + ci) * 1024 + px_base + o];
        }
        __syncthreads();
#pragma unroll
        for (int ci = 0; ci < 16; ++ci) {
            float4 wv = *(const float4*)&wtl[ci][o_off];
            float4 sv = *(const float4*)&ps[ci][px_off];
            acc[0][0] += wv.x * sv.x; acc[0][1] += wv.x * sv.y;
            acc[0][2] += wv.x * sv.z; acc[0][3] += wv.x * sv.w;
            acc[1][0] += wv.y * sv.x; acc[1][1] += wv.y * sv.y;
            acc[1][2] += wv.y * sv.z; acc[1][3] += wv.y * sv.w;
            acc[2][0] += wv.z * sv.x; acc[2][1] += wv.z * sv.y;
            acc[2][2] += wv.z * sv.z; acc[2][3] += wv.z * sv.w;
            acc[3][0] += wv.w * sv.x; acc[3][1] += wv.w * sv.y;
            acc[3][2] += wv.w * sv.z; acc[3][3] += wv.w * sv.w;
        }
        __syncthreads();
    }
#pragma unroll
    for (int c = 0; c < 4; ++c) {
        int o = o_base + o_off + c;
        if (o < 255)
            *(float4*)&out[(b * 255 + o) * 1024 + px_base + px_off] =
                make_float4(acc[c][0], acc[c][1], acc[c][2], acc[c][3]);
    }
}

extern "C" void kernel_launch(void* const* d_in, const int* in_sizes, int n_in,
                              void* d_out, int out_size, void* d_ws, size_t ws_size,
                              hipStream_t stream) {
    const float* x  = (const float*)d_in[0];
    const float* w1 = (const float*)d_in[1];
    const float* b1 = (const float*)d_in[2];
    const float* w2 = (const float*)d_in[3];
    const float* b2 = (const float*)d_in[4];
    const float* w3 = (const float*)d_in[5];
    const float* b3 = (const float*)d_in[6];
    const float* wd = (const float*)d_in[7];
    const float* bd = (const float*)d_in[8];
    float* out = (float*)d_out;

    // ws layout (256B headroom before s1 for left-edge aligned windows):
    //   s1  u8  [40][64][128][128] @ 256         (41,943,040)
    //   s2  u8  [40][128][64][64]  @ 41,943,296  (20,971,520)
    //   c2  f32 [40][128][64][64]  @ 62,914,816  (83,886,080)
    //   c3  f32 [40][256][32][32]  @ 146,800,896 (41,943,040)
    //   pooled f32 [4][256][1024]  @ 188,743,936 (4,194,304)
    //   wt2 f32 [576][128]         @ 192,938,240 (294,912)
    //   wt3 f32 [1152][256]        @ 193,233,152 (1,179,648)  end ~194.4 MB
    uint8_t* wsb = (uint8_t*)d_ws;
    uint8_t* s1     = wsb + 256;
    uint8_t* s2     = wsb + 41943296u;
    float*   c2     = (float*)(wsb + 62914816u);
    float*   c3     = (float*)(wsb + 146800896u);
    float*   pooled = (float*)(wsb + 188743936u);
    float*   wt2    = (float*)(wsb + 192938240u);
    float*   wt3    = (float*)(wsb + 193233152u);

    float alpha, beta;
    { uint32_t ab = 0x3F7383C6u; memcpy(&alpha, &ab, 4); }  // e^-0.05f
    { uint32_t bb = 0x3F519857u; memcpy(&beta,  &bb, 4); }  // e^-0.2f

    wtrans<<<288, 256, 0, stream>>>(w2, wt2, 576, 128);
    wtrans<<<1152, 256, 0, stream>>>(w3, wt3, 1152, 256);
    conv1_lif<<<dim3(16, 128, 4), 256, 0, stream>>>(x, w1, b1, s1, alpha, beta);
    // L2 conv: 64->128, 128->64, t-parallel. grid (4,32,40)=5120 blocks
    conv_g<64, 128, 128, 64, 16, 42, 2, 64, 0>
        <<<dim3(4, 32, 40), 256, 0, stream>>>(s1, wt2, c2);
    lif_s<128, 4096><<<dim3(4, 128, 4), 256, 0, stream>>>(c2, b2, s2, alpha, beta);
    // L3 conv: 128->256, 64->32, t-parallel. grid (1,64,40)=2560 blocks
    conv_g<128, 256, 64, 32, 8, 42, 2, 85, 1>
        <<<dim3(1, 64, 40), 256, 0, stream>>>(s2, wt3, c3);
    lif_mean<256, 1024><<<dim3(1, 256, 4), 256, 0, stream>>>(c3, b3, pooled, alpha, beta);
    det_conv<<<dim3(16, 4, 4), 256, 0, stream>>>(pooled, wd, bd, out);
}

// Round 12
// 707.416 us; speedup vs baseline: 3.7169x; 1.1179x over previous
//
#include <hip/hip_runtime.h>
#include <stdint.h>
#include <string.h>
#include <cmath>

// SpikingYOLO round 12: FMA-density attack. Numerics BIT-IDENTICAL to R9-R11
// (FMA-sequential f32 conv, k=(ci,kh,kw) ascending, kc=384 flushes at k=384/768,
// bias after, unfused f32 LIF, alpha=0x3F7383C6 beta=0x3F519857).
// R11 post-mortem: VALUBusy 82% but FMA density only ~67% (masks+cvt+addr).
// This round: 8co x 4px thread tile (96 FMA per 9-cvt window) + zero-padded u8
// spike buffers (no boundary masks). Per-output FMA chain order unchanged.

#define BB 4
#define TT 10

// padded plane geometry: rows -1..HIN-1 (HIN+1 rows), cols -4..HIN+3 (HIN+8)
// L2 input (s1p):  HIN=128: row stride 136 B, plane 129*136 = 17544 B
// L3 input (s2p):  HIN=64 : row stride 72 B,  plane 65*72   = 4680 B

// ------------------------------------------------ zero the pad borders
template<int RS_DW, int NROWS>
__global__ __launch_bounds__(256) void zpad(uint32_t* __restrict__ buf) {
    const int plane = blockIdx.x;
    const int j = threadIdx.x;
    uint32_t* p = buf + (size_t)plane * (RS_DW * NROWS);
    if (j < NROWS) p[j * RS_DW] = 0u;                    // cols -4..-1 of every row
    const int k = j - NROWS;
    if (k >= 0 && k < RS_DW - 1) p[k + 1] = 0u;          // rest of top pad row (-1)
}

// ---------------------------------------------------------------- conv1+LIF
// unchanged numerics from R9; writes u8 spikes into padded s1p layout.
__global__ __launch_bounds__(256) void conv1_lif(
    const float* __restrict__ x,    // [4,2,128,128,10]
    const float* __restrict__ w1,   // [64,2,3,3]
    const float* __restrict__ b1,   // [64]
    uint8_t* __restrict__ s1p,      // padded [40*64][129][136]
    float alpha, float beta)
{
    __shared__ float xs[2][3][10][10];   // [ci][kh][wi][t]
    __shared__ float wsh[18][64];        // [tap][co]
    const int tid = threadIdx.x;
    const int b = blockIdx.z, h = blockIdx.y, w0 = blockIdx.x * 8;

    for (int i = tid; i < 1152; i += 256) {
        int co = i & 63, tap = i >> 6;
        wsh[tap][co] = w1[co * 18 + tap];
    }
    for (int i = tid; i < 600; i += 256) {
        int t = i % 10; int rest = i / 10;
        int wi = rest % 10; rest /= 10;
        int kh = rest % 3; int ci = rest / 3;
        int hh = h - 1 + kh, ww = w0 - 1 + wi;
        float v = 0.f;
        if (hh >= 0 && hh < 128 && ww >= 0 && ww < 128)
            v = x[(((b * 2 + ci) * 128 + hh) * 128 + ww) * 10 + t];
        xs[ci][kh][wi][t] = v;
    }
    __syncthreads();

    const int px  = tid & 7;
    const int cog = (tid >> 3) * 2;
    float acc[2][10];
#pragma unroll
    for (int c = 0; c < 2; ++c)
#pragma unroll
        for (int t = 0; t < 10; ++t) acc[c][t] = 0.f;

#pragma unroll
    for (int tap = 0; tap < 18; ++tap) {
        const int ci = tap / 9, kh = (tap % 9) / 3, kw = tap % 3;
        float2 wv = *(const float2*)&wsh[tap][cog];
#pragma unroll
        for (int t = 0; t < 10; ++t) {
            float xv = xs[ci][kh][px + kw][t];
            acc[0][t] = __fmaf_rn(wv.x, xv, acc[0][t]);
            acc[1][t] = __fmaf_rn(wv.y, xv, acc[1][t]);
        }
    }
#pragma unroll
    for (int c = 0; c < 2; ++c) {
        const float bv = b1[cog + c];
        float syn = 0.f, mem = 0.f;
#pragma unroll
        for (int t = 0; t < 10; ++t) {
            float cur = __fadd_rn(acc[c][t], bv);
            syn = __fadd_rn(__fmul_rn(beta, syn), cur);
            mem = __fadd_rn(__fmul_rn(alpha, mem), syn);
            float sp = (mem >= 1.0f) ? 1.0f : 0.0f;
            mem = __fsub_rn(mem, sp);
            s1p[(uint32_t)((t * BB + b) * 64 + (cog + c)) * 17544u
                + (h + 1) * 136 + (w0 + px + 4)] = (uint8_t)sp;
        }
    }
}

// --------------------------------------------------- weight transpose kernel
__global__ __launch_bounds__(256) void wtrans(
    const float* __restrict__ w, float* __restrict__ wt, int K, int COUT)
{
    int i = blockIdx.x * 256 + threadIdx.x;
    if (i < K * COUT) {
        int k = i / COUT, co = i - k * COUT;
        wt[i] = w[co * K + k];
    }
}

// ------------------------------------------------- per-ci conv taps (inlined)
// 8co x 4px; padded input -> no masks. sv[c] = spike at in-col 8w4-1+c.
template<int COUT, int PLANE, int KHB, int KHE>
__device__ __forceinline__ void conv_ci8(
    int ci, const uint8_t* __restrict__ fb, const float* __restrict__ wt,
    int cob, const int off[3], float part[32])
{
    const uint8_t* p = fb + (uint32_t)ci * PLANE;
    uint32_t d0[3], d1[3], d2[3];
#pragma unroll
    for (int kh = KHB; kh < KHE; ++kh) {
        const uint8_t* q = p + off[kh];
        uint2 v = *(const uint2*)q;          // 8B-aligned (row stride % 8 == 0)
        d0[kh] = v.x; d1[kh] = v.y;
        d2[kh] = *(const uint32_t*)(q + 8);
    }
#pragma unroll
    for (int kh = KHB; kh < KHE; ++kh) {
        float sv[9];
        sv[0] = (float)(d0[kh] >> 24);
        sv[1] = (float)(d1[kh] & 0xffu);
        sv[2] = (float)((d1[kh] >> 8) & 0xffu);
        sv[3] = (float)((d1[kh] >> 16) & 0xffu);
        sv[4] = (float)(d1[kh] >> 24);
        sv[5] = (float)(d2[kh] & 0xffu);
        sv[6] = (float)((d2[kh] >> 8) & 0xffu);
        sv[7] = (float)((d2[kh] >> 16) & 0xffu);
        sv[8] = (float)(d2[kh] >> 24);
#pragma unroll
        for (int kw = 0; kw < 3; ++kw) {
            const float* wp = wt + (ci * 9 + kh * 3 + kw) * COUT + cob; // uniform -> s_load
#pragma unroll
            for (int co = 0; co < 8; ++co) {
                const float wv = wp[co];
#pragma unroll
                for (int j = 0; j < 4; ++j)
                    part[co * 4 + j] = __fmaf_rn(wv, sv[2 * j + kw], part[co * 4 + j]);
            }
        }
    }
}

// -------------------- stride-2 3x3 conv, t-parallel, currents out (no LIF)
// thread: 8co x 4px; padded u8 input; no LDS/barriers/masks.
template<int CIN, int COUT, int HOUT, int WTH, int PLANE, int RS,
         int F1CI, int F1KH, int F2CI, int F2KH>
__global__ __launch_bounds__(256) void conv_g8(
    const uint8_t* __restrict__ sin,   // padded planes [40*CIN][...]
    const float* __restrict__ wt,      // [CIN*9][COUT] transposed
    float* __restrict__ cur)           // [40,COUT,HOUT,HOUT] pre-bias currents
{
    const int tid = threadIdx.x;
    const int w4  = tid & (WTH - 1);
    const int hh  = blockIdx.x * (256 / WTH) + (tid / WTH);
    const int cob = blockIdx.y * 8;
    const int f   = blockIdx.z;

    const uint8_t* fb = sin + (size_t)f * CIN * PLANE;
    int off[3];
#pragma unroll
    for (int kh = 0; kh < 3; ++kh) off[kh] = (2 * hh + kh) * RS + 8 * w4;

    float part[32], tot[32];
#pragma unroll
    for (int n = 0; n < 32; ++n) { part[n] = 0.f; tot[n] = 0.f; }

    for (int ci = 0; ci < F1CI; ++ci)
        conv_ci8<COUT,PLANE,0,3>(ci, fb, wt, cob, off, part);
    // kc flush #1 at global k=384
    conv_ci8<COUT,PLANE,0,F1KH>(F1CI, fb, wt, cob, off, part);
#pragma unroll
    for (int n = 0; n < 32; ++n) { tot[n] = __fadd_rn(tot[n], part[n]); part[n] = 0.f; }
    conv_ci8<COUT,PLANE,F1KH,3>(F1CI, fb, wt, cob, off, part);
    if constexpr (F2CI < CIN) {
        for (int ci = F1CI + 1; ci < F2CI; ++ci)
            conv_ci8<COUT,PLANE,0,3>(ci, fb, wt, cob, off, part);
        // kc flush #2 at global k=768
        conv_ci8<COUT,PLANE,0,F2KH>(F2CI, fb, wt, cob, off, part);
#pragma unroll
        for (int n = 0; n < 32; ++n) { tot[n] = __fadd_rn(tot[n], part[n]); part[n] = 0.f; }
        conv_ci8<COUT,PLANE,F2KH,3>(F2CI, fb, wt, cob, off, part);
        for (int ci = F2CI + 1; ci < CIN; ++ci)
            conv_ci8<COUT,PLANE,0,3>(ci, fb, wt, cob, off, part);
    } else {
        for (int ci = F1CI + 1; ci < CIN; ++ci)
            conv_ci8<COUT,PLANE,0,3>(ci, fb, wt, cob, off, part);
    }

#pragma unroll
    for (int c = 0; c < 8; ++c) {
        float4 v = make_float4(__fadd_rn(tot[c*4+0], part[c*4+0]),
                               __fadd_rn(tot[c*4+1], part[c*4+1]),
                               __fadd_rn(tot[c*4+2], part[c*4+2]),
                               __fadd_rn(tot[c*4+3], part[c*4+3]));
        *(float4*)&cur[((uint32_t)(f * COUT + cob + c) * HOUT + hh) * HOUT + 4 * w4] = v;
    }
}

// ------------------------------------------ LIF scan over currents -> spikes
// writes u8 spikes into the PADDED s2p layout (interior only).
template<int COUT, int HW, int HOUTW, int RS, int PLANE>
__global__ __launch_bounds__(256) void lif_s(
    const float* __restrict__ cur, const float* __restrict__ bias,
    uint8_t* __restrict__ spk_p, float alpha, float beta)
{
    const int px = (blockIdx.x * 256 + threadIdx.x) * 4;
    const int co = blockIdx.y;
    const int b  = blockIdx.z;
    const int h  = px / HOUTW, w = px % HOUTW;
    const float bv = bias[co];
    float syn[4] = {0.f,0.f,0.f,0.f}, mem[4] = {0.f,0.f,0.f,0.f};
    for (int t = 0; t < TT; ++t) {
        const int f = t * BB + b;
        float4 v = *(const float4*)&cur[((uint32_t)(f * COUT + co)) * HW + px];
        const float vv[4] = {v.x, v.y, v.z, v.w};
        uint32_t pk = 0;
#pragma unroll
        for (int j = 0; j < 4; ++j) {
            float c = __fadd_rn(vv[j], bv);
            syn[j] = __fadd_rn(__fmul_rn(beta, syn[j]), c);
            mem[j] = __fadd_rn(__fmul_rn(alpha, mem[j]), syn[j]);
            bool sc = (mem[j] >= 1.0f);
            mem[j] = __fsub_rn(mem[j], sc ? 1.0f : 0.0f);
            pk |= (sc ? 1u : 0u) << (j * 8);
        }
        *(uint32_t*)&spk_p[(size_t)(f * COUT + co) * PLANE + (h + 1) * RS + (w + 4)] = pk;
    }
}

// ------------------------------------- LIF + time-mean -> pooled (layer 3)
template<int COUT, int HW>
__global__ __launch_bounds__(256) void lif_mean(
    const float* __restrict__ cur, const float* __restrict__ bias,
    float* __restrict__ pooled, float alpha, float beta)
{
    const int px = (blockIdx.x * 256 + threadIdx.x) * 4;
    const int co = blockIdx.y;
    const int b  = blockIdx.z;
    const float bv = bias[co];
    float syn[4] = {0.f,0.f,0.f,0.f}, mem[4] = {0.f,0.f,0.f,0.f};
    float sum[4] = {0.f,0.f,0.f,0.f};
    for (int t = 0; t < TT; ++t) {
        const int idx = ((t * BB + b) * COUT + co) * HW + px;
        float4 v = *(const float4*)&cur[idx];
        const float vv[4] = {v.x, v.y, v.z, v.w};
#pragma unroll
        for (int j = 0; j < 4; ++j) {
            float c = __fadd_rn(vv[j], bv);
            syn[j] = __fadd_rn(__fmul_rn(beta, syn[j]), c);
            mem[j] = __fadd_rn(__fmul_rn(alpha, mem[j]), syn[j]);
            bool sc = (mem[j] >= 1.0f);
            float sp = sc ? 1.0f : 0.0f;
            mem[j] = __fsub_rn(mem[j], sp);
            sum[j] = __fadd_rn(sum[j], sp);
        }
    }
    *(float4*)&pooled[(b * COUT + co) * HW + px] =
        make_float4(sum[0] / 10.0f, sum[1] / 10.0f, sum[2] / 10.0f, sum[3] / 10.0f);
}

// ------------------------------------------------------------------ det 1x1
__global__ __launch_bounds__(256) void det_conv(
    const float* __restrict__ pooled, // [4,256,1024]
    const float* __restrict__ wd,     // [255,256]
    const float* __restrict__ bd,     // [255]
    float* __restrict__ out)          // [4,255,1024]
{
    __shared__ float wtl[16][64];
    __shared__ float ps[16][64];
    const int tid = threadIdx.x;
    const int b = blockIdx.z;
    const int o_base = blockIdx.y * 64;
    const int px_base = blockIdx.x * 64;
    const int o_off = (tid >> 4) * 4;
    const int px_off = (tid & 15) * 4;
    float acc[4][4];
#pragma unroll
    for (int c = 0; c < 4; ++c) {
        int o = o_base + o_off + c;
        float bv = (o < 255) ? bd[o] : 0.f;
#pragma unroll
        for (int j = 0; j < 4; ++j) acc[c][j] = bv;
    }
    for (int cc = 0; cc < 16; ++cc) {
        for (int k = tid; k < 1024; k += 256) {
            int o = k & 63, ci = k >> 6;
            wtl[ci][o] = (o_base + o < 255) ? wd[(o_base + o) * 256 + cc * 16 + ci] : 0.f;
            ps[ci][o] = pooled[(b * 256 + cc * 16 + ci) * 1024 + px_base + o];
        }
        __syncthreads();
#pragma unroll
        for (int ci = 0; ci < 16; ++ci) {
            float4 wv = *(const float4*)&wtl[ci][o_off];
            float4 sv = *(const float4*)&ps[ci][px_off];
            acc[0][0] += wv.x * sv.x; acc[0][1] += wv.x * sv.y;
            acc[0][2] += wv.x * sv.z; acc[0][3] += wv.x * sv.w;
            acc[1][0] += wv.y * sv.x; acc[1][1] += wv.y * sv.y;
            acc[1][2] += wv.y * sv.z; acc[1][3] += wv.y * sv.w;
            acc[2][0] += wv.z * sv.x; acc[2][1] += wv.z * sv.y;
            acc[2][2] += wv.z * sv.z; acc[2][3] += wv.z * sv.w;
            acc[3][0] += wv.w * sv.x; acc[3][1] += wv.w * sv.y;
            acc[3][2] += wv.w * sv.z; acc[3][3] += wv.w * sv.w;
        }
        __syncthreads();
    }
#pragma unroll
    for (int c = 0; c < 4; ++c) {
        int o = o_base + o_off + c;
        if (o < 255)
            *(float4*)&out[(b * 255 + o) * 1024 + px_base + px_off] =
                make_float4(acc[c][0], acc[c][1], acc[c][2], acc[c][3]);
    }
}

extern "C" void kernel_launch(void* const* d_in, const int* in_sizes, int n_in,
                              void* d_out, int out_size, void* d_ws, size_t ws_size,
                              hipStream_t stream) {
    const float* x  = (const float*)d_in[0];
    const float* w1 = (const float*)d_in[1];
    const float* b1 = (const float*)d_in[2];
    const float* w2 = (const float*)d_in[3];
    const float* b2 = (const float*)d_in[4];
    const float* w3 = (const float*)d_in[5];
    const float* b3 = (const float*)d_in[6];
    const float* wd = (const float*)d_in[7];
    const float* bd = (const float*)d_in[8];
    float* out = (float*)d_out;

    // ws layout (c3 aliases s1p region -- s1p dead after L2 conv):
    //   s1p u8 [2560][17544]  @ 256          (44,912,640)   | c3 f32 41,943,040
    //   s2p u8 [5120][4680]   @ 44,912,896   (23,961,600)
    //   c2  f32 [40*128*4096] @ 68,874,496   (83,886,080)
    //   pooled f32            @ 152,760,576  (4,194,304)
    //   wt2 f32 [576][128]    @ 156,954,880  (294,912)
    //   wt3 f32 [1152][256]   @ 157,249,792  (1,179,648)    end 158,429,440
    uint8_t* wsb = (uint8_t*)d_ws;
    uint8_t* s1p    = wsb + 256;
    float*   c3     = (float*)(wsb + 256);
    uint8_t* s2p    = wsb + 44912896u;
    float*   c2     = (float*)(wsb + 68874496u);
    float*   pooled = (float*)(wsb + 152760576u);
    float*   wt2    = (float*)(wsb + 156954880u);
    float*   wt3    = (float*)(wsb + 157249792u);

    float alpha, beta;
    { uint32_t ab = 0x3F7383C6u; memcpy(&alpha, &ab, 4); }  // e^-0.05f
    { uint32_t bb = 0x3F519857u; memcpy(&beta,  &bb, 4); }  // e^-0.2f

    // zero pad borders (graph-safe, every call)
    zpad<34, 129><<<2560, 256, 0, stream>>>((uint32_t*)s1p);
    zpad<18, 65><<<5120, 256, 0, stream>>>((uint32_t*)s2p);
    wtrans<<<288, 256, 0, stream>>>(w2, wt2, 576, 128);
    wtrans<<<1152, 256, 0, stream>>>(w3, wt3, 1152, 256);
    conv1_lif<<<dim3(16, 128, 4), 256, 0, stream>>>(x, w1, b1, s1p, alpha, beta);
    // L2 conv: 64->128, 128->64. 8co x 4px; block 16 w4 x 16 rows; grid (4,16,40)
    conv_g8<64, 128, 64, 16, 17544, 136, 42, 2, 64, 0>
        <<<dim3(4, 16, 40), 256, 0, stream>>>(s1p, wt2, c2);
    // LIF L2 -> padded s2p spikes
    lif_s<128, 4096, 64, 72, 4680><<<dim3(4, 128, 4), 256, 0, stream>>>(c2, b2, s2p, alpha, beta);
    // L3 conv: 128->256, 64->32. 8co x 4px; block 8 w4 x 32 rows; grid (1,32,40)
    conv_g8<128, 256, 32, 8, 4680, 72, 42, 2, 85, 1>
        <<<dim3(1, 32, 40), 256, 0, stream>>>(s2p, wt3, c3);
    lif_mean<256, 1024><<<dim3(1, 256, 4), 256, 0, stream>>>(c3, b3, pooled, alpha, beta);
    det_conv<<<dim3(16, 4, 4), 256, 0, stream>>>(pooled, wd, bd, out);
}